// Round 1
// baseline (1242.403 us; speedup 1.0000x reference)
//
#include <hip/hip_runtime.h>

#define F 128
#define F4 32
#define EPS 1e-3f

// ---------------- init: zero the histogram ----------------
__global__ void init_counts(int* __restrict__ counts, int B) {
    int i = blockIdx.x * blockDim.x + threadIdx.x;
    if (i < B) counts[i] = 0;
}

// ---------------- histogram of graph_id ----------------
__global__ void hist_kernel(const int* __restrict__ gid, int* __restrict__ counts, int N) {
    int i = blockIdx.x * blockDim.x + threadIdx.x;
    int stride = gridDim.x * blockDim.x;
    for (; i < N; i += stride) atomicAdd(&counts[gid[i]], 1);
}

// ---------------- exclusive scan over counts (single block, B<=2048) ----------------
__global__ __launch_bounds__(256) void scan_kernel(const int* __restrict__ counts,
                                                   int* __restrict__ offsets,
                                                   int* __restrict__ cursors, int B) {
    const int tid = threadIdx.x;
    const int base = tid * 8;
    int local[8];
    int s = 0;
#pragma unroll
    for (int j = 0; j < 8; ++j) {
        int c = (base + j < B) ? counts[base + j] : 0;
        local[j] = s;
        s += c;
    }
    const int lane = tid & 63, wid = tid >> 6;
    int v = s;
#pragma unroll
    for (int off = 1; off < 64; off <<= 1) {
        int u = __shfl_up(v, off);
        if (lane >= off) v += u;
    }
    __shared__ int wsum[4];
    if (lane == 63) wsum[wid] = v;
    __syncthreads();
    int wbase = 0;
    for (int w = 0; w < wid; ++w) wbase += wsum[w];
    const int texcl = wbase + v - s;  // exclusive prefix for this thread's chunk
#pragma unroll
    for (int j = 0; j < 8; ++j) {
        if (base + j < B) {
            int o = texcl + local[j];
            offsets[base + j] = o;
            cursors[base + j] = o;
        }
    }
}

// ---------------- scatter node indices into per-graph buckets ----------------
__global__ void scatter_kernel(const int* __restrict__ gid, int* __restrict__ cursors,
                               int* __restrict__ perm, int N) {
    int i = blockIdx.x * blockDim.x + threadIdx.x;
    int stride = gridDim.x * blockDim.x;
    for (; i < N; i += stride) {
        int g = gid[i];
        int p = atomicAdd(&cursors[g], 1);
        perm[p] = i;
    }
}

// ---------------- per-graph reduction: sum & sumsq -> scale & shift ----------------
__global__ __launch_bounds__(256) void reduce_kernel(const float* __restrict__ values,
                                                     const int* __restrict__ perm,
                                                     const int* __restrict__ offsets,
                                                     const int* __restrict__ counts,
                                                     const float* __restrict__ gamma,
                                                     const float* __restrict__ beta,
                                                     const float* __restrict__ alpha,
                                                     float* __restrict__ scale,
                                                     float* __restrict__ shift) {
    const int b = blockIdx.x;
    const int start = offsets[b];
    const int cnt = counts[b];
    const int tid = threadIdx.x, lane = tid & 63, wid = tid >> 6;
    const int f0 = lane * 2;  // each lane owns features (f0, f0+1): 64 lanes * 8B = 512B/row
    float s0 = 0.f, s1 = 0.f, q0 = 0.f, q1 = 0.f;
    for (int r = wid; r < cnt; r += 4) {
        const int row = perm[start + r];
        const float2 v = *reinterpret_cast<const float2*>(values + (size_t)row * F + f0);
        s0 += v.x; s1 += v.y;
        q0 += v.x * v.x; q1 += v.y * v.y;
    }
    __shared__ float red[4][2][F];  // [wave][sum|sumsq][feature]  = 4 KiB
    red[wid][0][f0] = s0; red[wid][0][f0 + 1] = s1;
    red[wid][1][f0] = q0; red[wid][1][f0 + 1] = q1;
    __syncthreads();
    if (tid < F) {
        const int f = tid;
        const float sum = red[0][0][f] + red[1][0][f] + red[2][0][f] + red[3][0][f];
        const float sq  = red[0][1][f] + red[1][1][f] + red[2][1][f] + red[3][1][f];
        const float c = (float)(cnt > 0 ? cnt : 1);
        const float inv = 1.0f / c;
        const float Ev = sum * inv;            // E[v]
        const float m = Ev * alpha[f];         // shifted mean
        float var = sq * inv - 2.0f * m * Ev + m * m;  // E[(v-m)^2]
        var = fmaxf(var, 0.0f);
        const float rstd = rsqrtf(var + EPS);
        const float sc = gamma[f] * rstd;
        scale[b * F + f] = sc;
        shift[b * F + f] = beta[f] - m * sc;
    }
}

// ---------------- normalize: out = v*scale[g,f] + shift[g,f] ----------------
__global__ __launch_bounds__(256) void norm_kernel(const float4* __restrict__ values4,
                                                   const int* __restrict__ gid,
                                                   const float4* __restrict__ scale4,
                                                   const float4* __restrict__ shift4,
                                                   float4* __restrict__ out4,
                                                   long long total4) {
    long long i = (long long)blockIdx.x * blockDim.x + threadIdx.x;
    const long long stride = (long long)gridDim.x * blockDim.x;
    for (; i < total4; i += stride) {
        const int row = (int)(i >> 5);   // F4 = 32 float4 per row
        const int f4 = (int)(i & 31);
        const int g = gid[row];
        const float4 v = values4[i];
        const float4 sc = scale4[g * F4 + f4];
        const float4 sh = shift4[g * F4 + f4];
        float4 o;
        o.x = fmaf(v.x, sc.x, sh.x);
        o.y = fmaf(v.y, sc.y, sh.y);
        o.z = fmaf(v.z, sc.z, sh.z);
        o.w = fmaf(v.w, sc.w, sh.w);
        out4[i] = o;
    }
}

extern "C" void kernel_launch(void* const* d_in, const int* in_sizes, int n_in,
                              void* d_out, int out_size, void* d_ws, size_t ws_size,
                              hipStream_t stream) {
    const float* values = (const float*)d_in[0];
    const int* gid      = (const int*)d_in[1];
    // d_in[2] = reference_ids (unused; only its length B matters)
    const float* gamma  = (const float*)d_in[3];
    const float* beta   = (const float*)d_in[4];
    const float* alpha  = (const float*)d_in[5];
    float* out = (float*)d_out;

    const int N = in_sizes[1];
    const int B = in_sizes[2];

    // workspace layout (16B-aligned chunks)
    char* ws = (char*)d_ws;
    auto take = [&](size_t bytes) {
        char* p = ws;
        ws += (bytes + 15) & ~(size_t)15;
        return p;
    };
    int* counts  = (int*)take((size_t)B * sizeof(int));
    int* offsets = (int*)take((size_t)B * sizeof(int));
    int* cursors = (int*)take((size_t)B * sizeof(int));
    int* perm    = (int*)take((size_t)N * sizeof(int));
    float* scale = (float*)take((size_t)B * F * sizeof(float));
    float* shift = (float*)take((size_t)B * F * sizeof(float));

    init_counts<<<(B + 255) / 256, 256, 0, stream>>>(counts, B);
    hist_kernel<<<1024, 256, 0, stream>>>(gid, counts, N);
    scan_kernel<<<1, 256, 0, stream>>>(counts, offsets, cursors, B);
    scatter_kernel<<<1024, 256, 0, stream>>>(gid, cursors, perm, N);
    reduce_kernel<<<B, 256, 0, stream>>>(values, perm, offsets, counts,
                                         gamma, beta, alpha, scale, shift);
    const long long total4 = (long long)N * F4;
    norm_kernel<<<8192, 256, 0, stream>>>((const float4*)values, gid,
                                          (const float4*)scale, (const float4*)shift,
                                          (float4*)out, total4);
}